// Round 12
// baseline (120.247 us; speedup 1.0000x reference)
//
#include <hip/hip_runtime.h>
#include <hip/hip_bf16.h>

#define BB 8
#define CC 16
#define EE 256
#define HH 256
#define WW 256
#define EMB_ROW (EE*9)

typedef __attribute__((ext_vector_type(8)))  __bf16 bf16x8;
typedef __attribute__((ext_vector_type(16))) float  f32x16;
typedef __attribute__((ext_vector_type(4)))  float  f32x4;

// ---- LDS layout (bytes) ----
// W    : [9][32e][16c] bf16   @ 0       (9216 B)
// XRING: 4 slots x [258wp][16c] bf16 @ 9216, slot stride 8256 B
// EPI  : [32e][256w] f32      @ 42240   (32768 B)
#define LDS_X_OFF   9216
#define SLOT_BYTES  8256
#define LDS_EPI_OFF 42240
#define LDS_TOTAL   75008

#define NTASK 2064   // 8 c-pairs * 258 wp per staged row

__device__ __forceinline__ unsigned pack_bf2(float a, float b) {
    union { __hip_bfloat162 h; unsigned u; } t;
    t.h.x = __float2bfloat16(a);
    t.h.y = __float2bfloat16(b);
    return t.u;
}

// X-ring address swizzle: 32B cell per wp; XOR byte bit4 with wp bit2 so
// consecutive-wp b128 reads cover all 8 LDS granules (write & read agree).
__device__ __forceinline__ int xswz(int wp, int inner) {
    return ((wp << 5) | inner) ^ ((wp & 4) << 2);
}

// grid: (BB, 8 ez, 16 hc)  block: 512 (8 waves). Block = 32e x 256w x 16h.
// ez in grid.y / hc in grid.z: co-resident blocks per XCD share a narrow
// window of x h-rows (all e-tiles of the same hc run together) -> x streams
// through L2 once per batch instead of once per e-tile sweep.
__global__ __launch_bounds__(512, 4) void conv_fused(
    const float* __restrict__ x,        // [B][C][H][W] f32
    const int*   __restrict__ indices,  // [B][C]
    const float* __restrict__ emb,      // [64][E*9] f32
    const float* __restrict__ bias,     // [E]
    float*       __restrict__ out)      // [B][E][H][W] f32
{
    __shared__ __align__(16) char smem[LDS_TOTAL];
    char*  WB  = smem;
    char*  XB  = smem + LDS_X_OFF;
    float* EPI = (float*)(smem + LDS_EPI_OFF);

    const int b  = blockIdx.x;          // batch fastest -> XCD k handles batch k
    const int ez = blockIdx.y;          // 8 e-tiles of 32
    const int hc = blockIdx.z;          // 16 h-chunks of 16
    const int tid   = threadIdx.x;
    const int lane  = tid & 63;
    const int wid   = tid >> 6;         // 0..7
    const int l31   = lane & 31;
    const int lhalf = lane >> 5;
    const int e0 = ez * 32;
    const int w0 = wid * 32;
    const int h0 = hc * 16;

    // ---- W gather: thread (e = tid>>4, c = tid&15) pulls 9 contiguous taps
    {
        const int e = tid >> 4, c = tid & 15;
        const int idx = indices[b * CC + c];
        const float* wrow = emb + (size_t)idx * EMB_ROW + (size_t)(e0 + e) * 9;
        #pragma unroll
        for (int tap = 0; tap < 9; ++tap) {
            *reinterpret_cast<__hip_bfloat16*>(WB + tap * 1024 + e * 32 + c * 2) =
                __float2bfloat16(wrow[tap]);
        }
    }

    // ---- x staging: T14 split (issue loads early, ds_write late) ----
    float r0[5], r1[5];
    auto issue_loads = [&](int ir) {
        #pragma unroll
        for (int k = 0; k < 5; ++k) {
            const int u = tid + 512 * k;
            if (u < NTASK) {
                const int cp = u / 258;
                const int wp = u - cp * 258;
                const int iw = wp - 1;
                const bool v = ((unsigned)iw < 256u) && ((unsigned)ir < 256u);
                const float* p = x + (((size_t)(b * CC + 2 * cp) * HH + (ir & 255)) * WW + (iw & 255));
                r0[k] = v ? p[0] : 0.f;
                r1[k] = v ? p[HH * WW] : 0.f;
            }
        }
    };
    auto write_stage = [&](int ir) {
        const int slot = (ir + 1) & 3;
        #pragma unroll
        for (int k = 0; k < 5; ++k) {
            const int u = tid + 512 * k;
            if (u < NTASK) {
                const int cp = u / 258;
                const int wp = u - cp * 258;
                *reinterpret_cast<unsigned*>(XB + slot * SLOT_BYTES + xswz(wp, cp << 2)) =
                    pack_bf2(r0[k], r1[k]);
            }
        }
    };

    // prologue: rows h0-1, h0, h0+1 staged; loads for h0+2 left in flight
    issue_loads(h0 - 1); write_stage(h0 - 1);
    issue_loads(h0);     write_stage(h0);
    issue_loads(h0 + 1); write_stage(h0 + 1);
    issue_loads(h0 + 2);
    asm volatile("s_waitcnt lgkmcnt(0)" ::: "memory");
    __builtin_amdgcn_s_barrier();

    // A-frags from LDS W (once): lane l -> e = e0+l31, c = lhalf*8..+8
    bf16x8 afrag[9];
    #pragma unroll
    for (int tap = 0; tap < 9; ++tap)
        afrag[tap] = *reinterpret_cast<const bf16x8*>(WB + tap * 1024 + l31 * 32 + lhalf * 16);

    float bb[4];
    #pragma unroll
    for (int i = 0; i < 4; ++i) bb[i] = bias[e0 + wid * 4 + i];

    for (int h = h0; h < h0 + 16; ++h) {
        // write row h+2 (loads issued last iter), then issue loads for h+3
        if (h + 2 <= h0 + 16) write_stage(h + 2);
        if (h + 3 <= h0 + 16) issue_loads(h + 3);
        asm volatile("s_waitcnt lgkmcnt(0)" ::: "memory");
        __builtin_amdgcn_s_barrier();

        f32x16 acc;
        #pragma unroll
        for (int r = 0; r < 16; ++r) acc[r] = 0.f;

        #pragma unroll
        for (int kh = 0; kh < 3; ++kh) {
            const char* base = XB + ((h + kh) & 3) * SLOT_BYTES;  // slot(ir=h-1+kh)
            #pragma unroll
            for (int kw = 0; kw < 3; ++kw) {
                const int wp = w0 + l31 + kw;
                bf16x8 bfrag = *reinterpret_cast<const bf16x8*>(base + xswz(wp, lhalf << 4));
                acc = __builtin_amdgcn_mfma_f32_32x32x16_bf16(afrag[kh * 3 + kw], bfrag, acc, 0, 0, 0);
            }
        }

        // epilogue scatter (LDS), then coalesced 1KB-row nt stores
        #pragma unroll
        for (int r = 0; r < 16; ++r) {
            const int erow = (r & 3) + 8 * (r >> 2) + 4 * lhalf;
            EPI[erow * 256 + w0 + l31] = acc[r];
        }
        asm volatile("s_waitcnt lgkmcnt(0)" ::: "memory");
        __builtin_amdgcn_s_barrier();

        #pragma unroll
        for (int i = 0; i < 4; ++i) {
            const int e = wid * 4 + i;
            f32x4 v = *reinterpret_cast<const f32x4*>(&EPI[e * 256 + lane * 4]);
            v += bb[i];
            __builtin_nontemporal_store(v,
                reinterpret_cast<f32x4*>(&out[((size_t)(b * EE + e0 + e) * HH + h) * WW + lane * 4]));
        }
    }
}

extern "C" void kernel_launch(void* const* d_in, const int* in_sizes, int n_in,
                              void* d_out, int out_size, void* d_ws, size_t ws_size,
                              hipStream_t stream) {
    const float* x       = (const float*)d_in[0];
    const int*   indices = (const int*)  d_in[1];
    const float* emb     = (const float*)d_in[2];
    const float* bias    = (const float*)d_in[3];
    float*       out     = (float*)d_out;

    conv_fused<<<dim3(BB, 8, 16), dim3(512), 0, stream>>>(x, indices, emb, bias, out);
}

// Round 13
// 111.907 us; speedup vs baseline: 1.0745x; 1.0745x over previous
//
#include <hip/hip_runtime.h>
#include <hip/hip_bf16.h>

#define BB 8
#define CC 16
#define EE 256
#define HH 256
#define WW 256
#define EMB_ROW (EE*9)

typedef __attribute__((ext_vector_type(8)))  __bf16 bf16x8;
typedef __attribute__((ext_vector_type(16))) float  f32x16;
typedef __attribute__((ext_vector_type(4)))  float  f32x4;

// ---- LDS layout (bytes) ----
// W    : [9][32e][16c] bf16   @ 0       (9216 B)
// XRING: 4 slots x [258wp][16c] bf16 @ 9216, slot stride 8256 B
// EPI  : [32e][256w] f32      @ 42240   (32768 B)
#define LDS_X_OFF   9216
#define SLOT_BYTES  8256
#define LDS_EPI_OFF 42240
#define LDS_TOTAL   75008

#define NTASK 2064   // 8 c-pairs * 258 wp per staged row

__device__ __forceinline__ unsigned pack_bf2(float a, float b) {
    union { __hip_bfloat162 h; unsigned u; } t;
    t.h.x = __float2bfloat16(a);
    t.h.y = __float2bfloat16(b);
    return t.u;
}

// X-ring address swizzle: 32B cell per wp; XOR byte bit4 with wp bit2 so
// consecutive-wp b128 reads cover all 8 LDS granules (write & read agree).
__device__ __forceinline__ int xswz(int wp, int inner) {
    return ((wp << 5) | inner) ^ ((wp & 4) << 2);
}

// grid: (BB, 16 hc, 8 ez)  block: 512 (8 waves). Block = 32e x 256w x 16h.
// (R10 ordering: empirically best of the three grid layouts tried.)
__global__ __launch_bounds__(512, 4) void conv_fused(
    const float* __restrict__ x,        // [B][C][H][W] f32
    const int*   __restrict__ indices,  // [B][C]
    const float* __restrict__ emb,      // [64][E*9] f32
    const float* __restrict__ bias,     // [E]
    float*       __restrict__ out)      // [B][E][H][W] f32
{
    __shared__ __align__(16) char smem[LDS_TOTAL];
    char*  WB  = smem;
    char*  XB  = smem + LDS_X_OFF;
    float* EPI = (float*)(smem + LDS_EPI_OFF);

    const int b  = blockIdx.x;          // batch fastest -> XCD k handles batch k
    const int hc = blockIdx.y;          // 16 h-chunks of 16
    const int ez = blockIdx.z;          // 8 e-tiles of 32
    const int tid   = threadIdx.x;
    const int lane  = tid & 63;
    const int wid   = tid >> 6;         // 0..7
    const int l31   = lane & 31;
    const int lhalf = lane >> 5;
    const int e0 = ez * 32;
    const int w0 = wid * 32;
    const int h0 = hc * 16;

    // ---- W gather: thread (e = tid>>4, c = tid&15) pulls 9 contiguous taps
    {
        const int e = tid >> 4, c = tid & 15;
        const int idx = indices[b * CC + c];
        const float* wrow = emb + (size_t)idx * EMB_ROW + (size_t)(e0 + e) * 9;
        #pragma unroll
        for (int tap = 0; tap < 9; ++tap) {
            *reinterpret_cast<__hip_bfloat16*>(WB + tap * 1024 + e * 32 + c * 2) =
                __float2bfloat16(wrow[tap]);
        }
    }

    // ---- x staging: T14 split (issue loads early, ds_write late) ----
    float r0[5], r1[5];
    auto issue_loads = [&](int ir) {
        #pragma unroll
        for (int k = 0; k < 5; ++k) {
            const int u = tid + 512 * k;
            if (u < NTASK) {
                const int cp = u / 258;
                const int wp = u - cp * 258;
                const int iw = wp - 1;
                const bool v = ((unsigned)iw < 256u) && ((unsigned)ir < 256u);
                const float* p = x + (((size_t)(b * CC + 2 * cp) * HH + (ir & 255)) * WW + (iw & 255));
                r0[k] = v ? p[0] : 0.f;
                r1[k] = v ? p[HH * WW] : 0.f;
            }
        }
    };
    auto write_stage = [&](int ir) {
        const int slot = (ir + 1) & 3;
        #pragma unroll
        for (int k = 0; k < 5; ++k) {
            const int u = tid + 512 * k;
            if (u < NTASK) {
                const int cp = u / 258;
                const int wp = u - cp * 258;
                *reinterpret_cast<unsigned*>(XB + slot * SLOT_BYTES + xswz(wp, cp << 2)) =
                    pack_bf2(r0[k], r1[k]);
            }
        }
    };

    // prologue: rows h0-1, h0, h0+1 staged; loads for h0+2 left in flight
    issue_loads(h0 - 1); write_stage(h0 - 1);
    issue_loads(h0);     write_stage(h0);
    issue_loads(h0 + 1); write_stage(h0 + 1);
    issue_loads(h0 + 2);
    asm volatile("s_waitcnt lgkmcnt(0)" ::: "memory");
    __builtin_amdgcn_s_barrier();

    // A-frags from LDS W (once): lane l -> e = e0+l31, c = lhalf*8..+8
    bf16x8 afrag[9];
    #pragma unroll
    for (int tap = 0; tap < 9; ++tap)
        afrag[tap] = *reinterpret_cast<const bf16x8*>(WB + tap * 1024 + l31 * 32 + lhalf * 16);

    float bb[4];
    #pragma unroll
    for (int i = 0; i < 4; ++i) bb[i] = bias[e0 + wid * 4 + i];

    for (int h = h0; h < h0 + 16; ++h) {
        // NOTE: r0/r1 still hold row h+2's loads here. We deliberately hold
        // them one more statement: nothing below reads them until write_stage.
        // write row h+2 (loads issued last iter), then issue loads for h+3.
        // write_stage FIRST would stall on vmcnt before issuing h+3; but we
        // need r0/r1 freed before reloading -> split: issue into fresh regs
        // is not expressible here, so keep order but the compiler's register
        // allocator double-buffers r0/r1 across the two lambdas when legal.
        if (h + 2 <= h0 + 16) write_stage(h + 2);
        if (h + 3 <= h0 + 16) issue_loads(h + 3);
        asm volatile("s_waitcnt lgkmcnt(0)" ::: "memory");
        __builtin_amdgcn_s_barrier();

        f32x16 acc;
        #pragma unroll
        for (int r = 0; r < 16; ++r) acc[r] = 0.f;

        #pragma unroll
        for (int kh = 0; kh < 3; ++kh) {
            const char* base = XB + ((h + kh) & 3) * SLOT_BYTES;  // slot(ir=h-1+kh)
            #pragma unroll
            for (int kw = 0; kw < 3; ++kw) {
                const int wp = w0 + l31 + kw;
                bf16x8 bfrag = *reinterpret_cast<const bf16x8*>(base + xswz(wp, lhalf << 4));
                acc = __builtin_amdgcn_mfma_f32_32x32x16_bf16(afrag[kh * 3 + kw], bfrag, acc, 0, 0, 0);
            }
        }

        // epilogue scatter (LDS), then coalesced 1KB-row nt stores
        #pragma unroll
        for (int r = 0; r < 16; ++r) {
            const int erow = (r & 3) + 8 * (r >> 2) + 4 * lhalf;
            EPI[erow * 256 + w0 + l31] = acc[r];
        }
        asm volatile("s_waitcnt lgkmcnt(0)" ::: "memory");
        __builtin_amdgcn_s_barrier();

        #pragma unroll
        for (int i = 0; i < 4; ++i) {
            const int e = wid * 4 + i;
            f32x4 v = *reinterpret_cast<const f32x4*>(&EPI[e * 256 + lane * 4]);
            v += bb[i];
            __builtin_nontemporal_store(v,
                reinterpret_cast<f32x4*>(&out[((size_t)(b * EE + e0 + e) * HH + h) * WW + lane * 4]));
        }
    }
}

extern "C" void kernel_launch(void* const* d_in, const int* in_sizes, int n_in,
                              void* d_out, int out_size, void* d_ws, size_t ws_size,
                              hipStream_t stream) {
    const float* x       = (const float*)d_in[0];
    const int*   indices = (const int*)  d_in[1];
    const float* emb     = (const float*)d_in[2];
    const float* bias    = (const float*)d_in[3];
    float*       out     = (float*)d_out;

    conv_fused<<<dim3(BB, 16, 8), dim3(512), 0, stream>>>(x, indices, emb, bias, out);
}